// Round 1
// baseline (720.923 us; speedup 1.0000x reference)
//
#include <hip/hip_runtime.h>
#include <math.h>

#define BB 4096
#define DD 1024
#define TT 50
#define NKS 13108      // ceil(131072/10)
#define NPOS 16

// ---------------------------------------------------------------------------
// Kernel 1: pack each label row (T=50 pairs of {0,1}) into three 50-bit masks
//   p0 = pure-l0 one-hot (1,0), p1 = pure-l1 (0,1), dd = double (1,1)
// One wave per row; lane t handles label slot t; __ballot builds the bitset.
// ---------------------------------------------------------------------------
__global__ __launch_bounds__(256) void label_codes(const int* __restrict__ labels,
                                                   unsigned long long* __restrict__ omask,
                                                   int nrows, int row_mult) {
    int w    = (blockIdx.x * blockDim.x + threadIdx.x) >> 6;
    int lane = threadIdx.x & 63;
    if (w >= nrows) return;
    const int2* p = (const int2*)(labels + (size_t)w * row_mult);
    int l0 = 0, l1 = 0;
    if (lane < TT) { int2 ll = p[lane]; l0 = ll.x; l1 = ll.y; }
    bool a = (lane < TT);
    unsigned long long p0 = __ballot(a && l0 && !l1);
    unsigned long long p1 = __ballot(a && l1 && !l0);
    unsigned long long dd = __ballot(a && l0 && l1);
    if (lane == 0) {
        omask[(size_t)w*3 + 0] = p0;
        omask[(size_t)w*3 + 1] = p1;
        omask[(size_t)w*3 + 2] = dd;
    }
}

// ---------------------------------------------------------------------------
// Kernel 2: per b, ordered scan over k chunks of 256; mask iff
//   popc(ss)*1 + popc(dd)*s + popc(mix)*v >= 25  (== mean over T >= 0.5)
// Collect first 16 masked k (in k order) + count, early exit.
// ---------------------------------------------------------------------------
__global__ __launch_bounds__(256) void scan_mask(const unsigned long long* __restrict__ bmask,
                                                 const unsigned long long* __restrict__ kmask,
                                                 int* __restrict__ list,
                                                 int* __restrict__ cnt) {
    int b   = blockIdx.x;
    int tid = threadIdx.x;
    int lane = tid & 63, wid = tid >> 6;

    unsigned long long pA0 = bmask[(size_t)b*3 + 0];
    unsigned long long pA1 = bmask[(size_t)b*3 + 1];
    unsigned long long dA  = bmask[(size_t)b*3 + 2];
    unsigned long long sA  = pA0 | pA1;

    const float v = 1.0f / (sqrtf(2.0f) + 1e-8f);  // mixed (1,1)x(1,0) dot
    const float s = v*v + v*v;                      // (1,1)x(1,1) dot

    __shared__ int wcnt[4];
    unsigned long long lmask = (1ull << lane) - 1ull;

    int found = 0;
    for (int base = 0; base < NKS; base += 256) {
        int kk = base + tid;
        bool m = false;
        if (kk < NKS) {
            unsigned long long pK0 = kmask[(size_t)kk*3 + 0];
            unsigned long long pK1 = kmask[(size_t)kk*3 + 1];
            unsigned long long dK  = kmask[(size_t)kk*3 + 2];
            unsigned long long sK  = pK0 | pK1;
            unsigned long long mss = (pA0 & pK0) | (pA1 & pK1);
            unsigned long long mdd = dA & dK;
            unsigned long long mix = (dA & sK) | (sA & dK);
            float sum = (float)__popcll(mss) + (float)__popcll(mdd)*s + (float)__popcll(mix)*v;
            m = (sum >= 25.0f);
        }
        unsigned long long bal = __ballot(m);
        if (lane == 0) wcnt[wid] = __popcll(bal);
        __syncthreads();
        int w0 = wcnt[0], w1 = wcnt[1], w2 = wcnt[2], w3 = wcnt[3];
        int woff = (wid > 0 ? w0 : 0) + (wid > 1 ? w1 : 0) + (wid > 2 ? w2 : 0);
        if (m) {
            int pos = found + woff + __popcll(bal & lmask);
            if (pos < NPOS) list[b*NPOS + pos] = kk;
        }
        found += w0 + w1 + w2 + w3;
        __syncthreads();
        if (found >= NPOS) break;
    }
    if (tid == 0) cnt[b] = found < NPOS ? found : NPOS;
}

// ---------------------------------------------------------------------------
// Kernel 3: per b, dot(x_q[b], qf[kk*10]) and ||row||^2 in one pass for the
// <=16 selected rows; softplus(-2*cos); atomicAdd mean into out.
// ---------------------------------------------------------------------------
__device__ inline float2 block_reduce2(float a, float b, float* lds) {
    for (int o = 32; o > 0; o >>= 1) {
        a += __shfl_down(a, o);
        b += __shfl_down(b, o);
    }
    int lane = threadIdx.x & 63, wid = threadIdx.x >> 6;
    if (lane == 0) { lds[wid*2] = a; lds[wid*2 + 1] = b; }
    __syncthreads();
    float2 r;
    r.x = lds[0] + lds[2] + lds[4] + lds[6];
    r.y = lds[1] + lds[3] + lds[5] + lds[7];
    __syncthreads();   // protect lds before next call
    return r;
}

__global__ __launch_bounds__(256) void loss_kernel(const float* __restrict__ x_q,
                                                   const float* __restrict__ qf,
                                                   const int* __restrict__ list,
                                                   const int* __restrict__ cnt,
                                                   float* __restrict__ out) {
    int b   = blockIdx.x;
    int tid = threadIdx.x;
    __shared__ float red[8];

    const float4* xqv = (const float4*)(x_q + (size_t)b * DD);
    float4 xq = xqv[tid];
    float nn = xq.x*xq.x + xq.y*xq.y + xq.z*xq.z + xq.w*xq.w;
    float2 nrm = block_reduce2(nn, 0.0f, red);
    float nq = sqrtf(nrm.x) + 1e-8f;

    int count = cnt[b];
    float per_anchor = 0.0f;
    for (int j = 0; j < count; ++j) {
        int kk = list[b*NPOS + j];
        const float4* rv = (const float4*)(qf + (size_t)kk * 10 * DD);
        float4 r = rv[tid];
        float dotp = xq.x*r.x + xq.y*r.y + xq.z*r.z + xq.w*r.w;
        float nk   = r.x*r.x + r.y*r.y + r.z*r.z + r.w*r.w;
        float2 rr = block_reduce2(dotp, nk, red);
        if (tid == 0) {
            float denom = nq * (sqrtf(rr.y) + 1e-8f);
            float sims = (rr.x / denom) * 2.0f;             // / TEMPERATURE(0.5)
            float z = -sims;                                // loss = softplus(-sims)
            per_anchor += fmaxf(z, 0.0f) + log1pf(expf(-fabsf(z)));
        }
    }
    if (tid == 0 && count > 0) {
        atomicAdd(out, per_anchor / (float)count * (1.0f / (float)BB));
    }
}

extern "C" void kernel_launch(void* const* d_in, const int* in_sizes, int n_in,
                              void* d_out, int out_size, void* d_ws, size_t ws_size,
                              hipStream_t stream) {
    const float* x_q            = (const float*)d_in[0];
    const int*   x_label        = (const int*)d_in[1];
    const float* queue_features = (const float*)d_in[2];
    const int*   queue_labels   = (const int*)d_in[3];
    float* out = (float*)d_out;

    unsigned long long* bmask = (unsigned long long*)d_ws;     // B*3 u64
    unsigned long long* kmask = bmask + (size_t)BB * 3;        // NKS*3 u64
    int* list = (int*)(kmask + (size_t)NKS * 3);               // B*16 int
    int* cnt  = list + (size_t)BB * NPOS;                      // B int

    hipMemsetAsync(d_out, 0, sizeof(float), stream);

    // b-side: 4096 rows, row stride 100 ints; exactly 1024 blocks of 4 waves
    label_codes<<<BB*64/256, 256, 0, stream>>>(x_label, bmask, BB, TT*2);
    // k-side: 13108 strided rows, row stride 10*100 ints; 3277 blocks exactly
    label_codes<<<(NKS*64 + 255)/256, 256, 0, stream>>>(queue_labels, kmask, NKS, TT*2*10);

    scan_mask<<<BB, 256, 0, stream>>>(bmask, kmask, list, cnt);
    loss_kernel<<<BB, 256, 0, stream>>>(x_q, queue_features, list, cnt, out);
}

// Round 2
// 710.060 us; speedup vs baseline: 1.0153x; 1.0153x over previous
//
#include <hip/hip_runtime.h>
#include <math.h>

#define BB 4096
#define DD 1024
#define TT 50
#define NKS 13108      // ceil(131072/10)
#define NPOS 16

// ---------------------------------------------------------------------------
// Kernel 1: pack each label row (T=50 pairs of {0,1}) into three 50-bit masks
//   p0 = pure-l0 one-hot (1,0), p1 = pure-l1 (0,1), dd = double (1,1)
// One wave per row; lane t handles label slot t; __ballot builds the bitset.
// ---------------------------------------------------------------------------
__global__ __launch_bounds__(256) void label_codes(const int* __restrict__ labels,
                                                   unsigned long long* __restrict__ omask,
                                                   int nrows, int row_mult) {
    int w    = (blockIdx.x * blockDim.x + threadIdx.x) >> 6;
    int lane = threadIdx.x & 63;
    if (w >= nrows) return;
    const int2* p = (const int2*)(labels + (size_t)w * row_mult);
    int l0 = 0, l1 = 0;
    if (lane < TT) { int2 ll = p[lane]; l0 = ll.x; l1 = ll.y; }
    bool a = (lane < TT);
    unsigned long long p0 = __ballot(a && l0 && !l1);
    unsigned long long p1 = __ballot(a && l1 && !l0);
    unsigned long long dd = __ballot(a && l0 && l1);
    if (lane == 0) {
        omask[(size_t)w*3 + 0] = p0;
        omask[(size_t)w*3 + 1] = p1;
        omask[(size_t)w*3 + 2] = dd;
    }
}

// ---------------------------------------------------------------------------
// Kernel 2: per b, ordered scan over k chunks of 256; mask iff
//   popc(ss)*1 + popc(dd)*s + popc(mix)*v >= 25  (== mean over T >= 0.5)
// Collect first 16 masked k (in k order) + count, early exit.
// ---------------------------------------------------------------------------
__global__ __launch_bounds__(256) void scan_mask(const unsigned long long* __restrict__ bmask,
                                                 const unsigned long long* __restrict__ kmask,
                                                 int* __restrict__ list,
                                                 int* __restrict__ cnt) {
    int b   = blockIdx.x;
    int tid = threadIdx.x;
    int lane = tid & 63, wid = tid >> 6;

    unsigned long long pA0 = bmask[(size_t)b*3 + 0];
    unsigned long long pA1 = bmask[(size_t)b*3 + 1];
    unsigned long long dA  = bmask[(size_t)b*3 + 2];
    unsigned long long sA  = pA0 | pA1;

    const float v = 1.0f / (sqrtf(2.0f) + 1e-8f);  // mixed (1,1)x(1,0) dot
    const float s = v*v + v*v;                      // (1,1)x(1,1) dot

    __shared__ int wcnt[4];
    unsigned long long lmask = (1ull << lane) - 1ull;

    int found = 0;
    for (int base = 0; base < NKS; base += 256) {
        int kk = base + tid;
        bool m = false;
        if (kk < NKS) {
            unsigned long long pK0 = kmask[(size_t)kk*3 + 0];
            unsigned long long pK1 = kmask[(size_t)kk*3 + 1];
            unsigned long long dK  = kmask[(size_t)kk*3 + 2];
            unsigned long long sK  = pK0 | pK1;
            unsigned long long mss = (pA0 & pK0) | (pA1 & pK1);
            unsigned long long mdd = dA & dK;
            unsigned long long mix = (dA & sK) | (sA & dK);
            float sum = (float)__popcll(mss) + (float)__popcll(mdd)*s + (float)__popcll(mix)*v;
            m = (sum >= 25.0f);
        }
        unsigned long long bal = __ballot(m);
        if (lane == 0) wcnt[wid] = __popcll(bal);
        __syncthreads();
        int w0 = wcnt[0], w1 = wcnt[1], w2 = wcnt[2], w3 = wcnt[3];
        int woff = (wid > 0 ? w0 : 0) + (wid > 1 ? w1 : 0) + (wid > 2 ? w2 : 0);
        if (m) {
            int pos = found + woff + __popcll(bal & lmask);
            if (pos < NPOS) list[b*NPOS + pos] = kk;
        }
        found += w0 + w1 + w2 + w3;
        __syncthreads();
        if (found >= NPOS) break;
    }
    if (tid == 0) cnt[b] = found < NPOS ? found : NPOS;
}

// ---------------------------------------------------------------------------
// Kernel 3: per b, dot(x_q[b], qf[kk*10]) and ||row||^2 in one pass for the
// <=16 selected rows; softplus(-2*cos); write per-b partial (NO atomics --
// 4096-way single-address atomic contention cost ~600us in R1).
// ---------------------------------------------------------------------------
__device__ inline float2 block_reduce2(float a, float b, float* lds) {
    for (int o = 32; o > 0; o >>= 1) {
        a += __shfl_down(a, o);
        b += __shfl_down(b, o);
    }
    int lane = threadIdx.x & 63, wid = threadIdx.x >> 6;
    if (lane == 0) { lds[wid*2] = a; lds[wid*2 + 1] = b; }
    __syncthreads();
    float2 r;
    r.x = lds[0] + lds[2] + lds[4] + lds[6];
    r.y = lds[1] + lds[3] + lds[5] + lds[7];
    __syncthreads();   // protect lds before next call
    return r;
}

__global__ __launch_bounds__(256) void loss_kernel(const float* __restrict__ x_q,
                                                   const float* __restrict__ qf,
                                                   const int* __restrict__ list,
                                                   const int* __restrict__ cnt,
                                                   float* __restrict__ per_b) {
    int b   = blockIdx.x;
    int tid = threadIdx.x;
    __shared__ float red[8];

    const float4* xqv = (const float4*)(x_q + (size_t)b * DD);
    float4 xq = xqv[tid];
    float nn = xq.x*xq.x + xq.y*xq.y + xq.z*xq.z + xq.w*xq.w;
    float2 nrm = block_reduce2(nn, 0.0f, red);
    float nq = sqrtf(nrm.x) + 1e-8f;

    int count = cnt[b];
    float per_anchor = 0.0f;
    for (int j = 0; j < count; ++j) {
        int kk = list[b*NPOS + j];
        const float4* rv = (const float4*)(qf + (size_t)kk * 10 * DD);
        float4 r = rv[tid];
        float dotp = xq.x*r.x + xq.y*r.y + xq.z*r.z + xq.w*r.w;
        float nk   = r.x*r.x + r.y*r.y + r.z*r.z + r.w*r.w;
        float2 rr = block_reduce2(dotp, nk, red);
        if (tid == 0) {
            float denom = nq * (sqrtf(rr.y) + 1e-8f);
            float sims = (rr.x / denom) * 2.0f;             // / TEMPERATURE(0.5)
            float z = -sims;                                // loss = softplus(-sims)
            per_anchor += fmaxf(z, 0.0f) + log1pf(expf(-fabsf(z)));
        }
    }
    if (tid == 0) {
        per_b[b] = (count > 0) ? per_anchor / (float)count : 0.0f;
    }
}

// ---------------------------------------------------------------------------
// Kernel 4: single-block tree reduction of the 4096 per-b partials -> mean.
// ---------------------------------------------------------------------------
__global__ __launch_bounds__(256) void final_reduce(const float* __restrict__ per_b,
                                                    float* __restrict__ out) {
    int tid = threadIdx.x;
    float s = 0.0f;
    for (int i = tid; i < BB; i += 256) s += per_b[i];
    for (int o = 32; o > 0; o >>= 1) s += __shfl_down(s, o);
    __shared__ float red[4];
    int lane = tid & 63, wid = tid >> 6;
    if (lane == 0) red[wid] = s;
    __syncthreads();
    if (tid == 0) out[0] = (red[0] + red[1] + red[2] + red[3]) * (1.0f / (float)BB);
}

extern "C" void kernel_launch(void* const* d_in, const int* in_sizes, int n_in,
                              void* d_out, int out_size, void* d_ws, size_t ws_size,
                              hipStream_t stream) {
    const float* x_q            = (const float*)d_in[0];
    const int*   x_label        = (const int*)d_in[1];
    const float* queue_features = (const float*)d_in[2];
    const int*   queue_labels   = (const int*)d_in[3];
    float* out = (float*)d_out;

    unsigned long long* bmask = (unsigned long long*)d_ws;     // B*3 u64
    unsigned long long* kmask = bmask + (size_t)BB * 3;        // NKS*3 u64
    int* list  = (int*)(kmask + (size_t)NKS * 3);              // B*16 int
    int* cnt   = list + (size_t)BB * NPOS;                     // B int
    float* per_b = (float*)(cnt + BB);                         // B float

    // b-side: 4096 rows, row stride 100 ints; exactly 1024 blocks of 4 waves
    label_codes<<<BB*64/256, 256, 0, stream>>>(x_label, bmask, BB, TT*2);
    // k-side: 13108 strided rows, row stride 10*100 ints; 3277 blocks exactly
    label_codes<<<(NKS*64 + 255)/256, 256, 0, stream>>>(queue_labels, kmask, NKS, TT*2*10);

    scan_mask<<<BB, 256, 0, stream>>>(bmask, kmask, list, cnt);
    loss_kernel<<<BB, 256, 0, stream>>>(x_q, queue_features, list, cnt, per_b);
    final_reduce<<<1, 256, 0, stream>>>(per_b, out);
}